// Round 1
// baseline (556.626 us; speedup 1.0000x reference)
//
#include <hip/hip_runtime.h>
#include <hip/hip_bf16.h>

#define NN 8192
#define FF 512
#define HH 512
#define CC 64
#define NS_TOTAL 557056      // 512*512 + 512*512 + 64*512
#define KSEL 278529u         // 1 + round(0.5 * (557056-1))
#define MAXNBR 96

// ---------------- threshold: exact radix select over |S| bit patterns ----------------

__global__ void hist_kernel(const float* __restrict__ S0, const float* __restrict__ S1,
                            const float* __restrict__ S2, unsigned* __restrict__ hist,
                            const unsigned* __restrict__ sel, int pass) {
    int idx = blockIdx.x * blockDim.x + threadIdx.x;
    if (idx >= NS_TOTAL) return;
    float v = (idx < 262144) ? S0[idx] : (idx < 524288) ? S1[idx - 262144] : S2[idx - 524288];
    unsigned key = __float_as_uint(fabsf(v));
    if (pass == 0) {
        atomicAdd(&hist[key >> 16], 1u);
    } else {
        if ((key >> 16) == sel[0]) atomicAdd(&hist[key & 0xffffu], 1u);
    }
}

__global__ void select_kernel(const unsigned* __restrict__ hist, unsigned* __restrict__ sel,
                              unsigned kFixed, int mode) {
    __shared__ unsigned part[256];
    __shared__ unsigned chunkbuf[256];
    __shared__ int chunkId;
    __shared__ unsigned cumBase;
    unsigned k = (mode == 0) ? kFixed : sel[1];
    int t = threadIdx.x;
    unsigned s = 0;
    for (int i = 0; i < 256; ++i) s += hist[t * 256 + i];
    part[t] = s;
    __syncthreads();
    if (t == 0) {
        unsigned cum = 0; int ch = 0;
        while (ch < 255 && cum + part[ch] < k) { cum += part[ch]; ch++; }
        chunkId = ch; cumBase = cum;
    }
    __syncthreads();
    chunkbuf[t] = hist[chunkId * 256 + t];
    __syncthreads();
    if (t == 0) {
        unsigned cum = cumBase;
        int b = 0;
        while (b < 255 && cum + chunkbuf[b] < k) { cum += chunkbuf[b]; b++; }
        unsigned bin = (unsigned)chunkId * 256u + (unsigned)b;
        if (mode == 0) { sel[0] = bin; sel[1] = k - cum; }
        else           { sel[2] = ((sel[0] << 16) | bin); }   // float bits of threshold
    }
}

// ---------------- masked weights ----------------

__global__ void mask_kernel(const float* __restrict__ W0, const float* __restrict__ W1,
                            const float* __restrict__ W2, const float* __restrict__ S0,
                            const float* __restrict__ S1, const float* __restrict__ S2,
                            float* __restrict__ Wm0, float* __restrict__ Wm1,
                            float* __restrict__ Wm2, const unsigned* __restrict__ sel) {
    int idx = blockIdx.x * blockDim.x + threadIdx.x;
    if (idx >= NS_TOTAL) return;
    float thr = __uint_as_float(sel[2]);
    if (idx < 262144) {
        Wm0[idx] = W0[idx] * ((fabsf(S0[idx]) > thr) ? 1.f : 0.f);
    } else if (idx < 524288) {
        int i = idx - 262144;
        Wm1[i] = W1[i] * ((fabsf(S1[i]) > thr) ? 1.f : 0.f);
    } else {
        int i = idx - 524288;
        Wm2[i] = W2[i] * ((fabsf(S2[i]) > thr) ? 1.f : 0.f);
    }
}

// ---------------- adjacency: degree + neighbor extraction (one pass over 256MB) ----------------

__global__ __launch_bounds__(256) void deg_kernel(const float* __restrict__ adj,
                                                  int* __restrict__ nnz, int* __restrict__ colsI,
                                                  float* __restrict__ dis) {
    int row = blockIdx.x;
    __shared__ int cnt;
    if (threadIdx.x == 0) cnt = 0;
    __syncthreads();
    const float4* arow = (const float4*)(adj + (size_t)row * NN);
    int* cp = colsI + (size_t)row * MAXNBR;
    for (int c4 = threadIdx.x; c4 < NN / 4; c4 += 256) {
        float4 v = arow[c4];
        int base = c4 * 4;
        float vv[4] = {v.x, v.y, v.z, v.w};
#pragma unroll
        for (int kq = 0; kq < 4; ++kq) {
            int col = base + kq;
            if (vv[kq] != 0.f || col == row) {
                int s = atomicAdd(&cnt, 1);
                if (s < MAXNBR) cp[s] = col;
            }
        }
    }
    __syncthreads();
    if (threadIdx.x == 0) {
        int c = cnt;
        nnz[row] = (c < MAXNBR) ? c : MAXNBR;
        dis[row] = rsqrtf((float)c);   // deg >= 1 always (self loop)
    }
}

// ---------------- f32 GEMM: C[M,Nn] = A[M,K] * B[Nn,K]^T ----------------

__global__ __launch_bounds__(256) void gemm_nt64(const float* __restrict__ A,
                                                 const float* __restrict__ B,
                                                 float* __restrict__ C,
                                                 int M, int Nn, int K) {
    __shared__ float As[16][68];
    __shared__ float Bs[16][68];
    const int bm = blockIdx.x * 64;
    const int bn = blockIdx.y * 64;
    const int tid = threadIdx.x;
    const int tn = tid & 15;    // col group (coalesced C writes)
    const int tm = tid >> 4;    // row group
    float acc[4][4] = {{0.f}};
    for (int k0 = 0; k0 < K; k0 += 16) {
        int li = tid * 4;
        int r = li >> 4;     // 0..63
        int c = li & 15;     // 0,4,8,12
        float4 av = *(const float4*)(A + (size_t)(bm + r) * K + (k0 + c));
        float4 bv = *(const float4*)(B + (size_t)(bn + r) * K + (k0 + c));
        As[c + 0][r] = av.x; As[c + 1][r] = av.y; As[c + 2][r] = av.z; As[c + 3][r] = av.w;
        Bs[c + 0][r] = bv.x; Bs[c + 1][r] = bv.y; Bs[c + 2][r] = bv.z; Bs[c + 3][r] = bv.w;
        __syncthreads();
#pragma unroll
        for (int kk = 0; kk < 16; ++kk) {
            float4 a = *(const float4*)&As[kk][tm * 4];
            float4 b = *(const float4*)&Bs[kk][tn * 4];
            acc[0][0] += a.x * b.x; acc[0][1] += a.x * b.y; acc[0][2] += a.x * b.z; acc[0][3] += a.x * b.w;
            acc[1][0] += a.y * b.x; acc[1][1] += a.y * b.y; acc[1][2] += a.y * b.z; acc[1][3] += a.y * b.w;
            acc[2][0] += a.z * b.x; acc[2][1] += a.z * b.y; acc[2][2] += a.z * b.z; acc[2][3] += a.z * b.w;
            acc[3][0] += a.w * b.x; acc[3][1] += a.w * b.y; acc[3][2] += a.w * b.z; acc[3][3] += a.w * b.w;
        }
        __syncthreads();
    }
#pragma unroll
    for (int i = 0; i < 4; ++i) {
        float4 o = make_float4(acc[i][0], acc[i][1], acc[i][2], acc[i][3]);
        *(float4*)(C + (size_t)(bm + tm * 4 + i) * Nn + bn + tn * 4) = o;
    }
}

// ---------------- SpMM: Hout[row,:] = dis[row] * sum_nbr dis[c] * Hin[c,:] ----------------

__global__ void spmm512(const int* __restrict__ nnz, const int* __restrict__ colsI,
                        const float* __restrict__ dis, const float* __restrict__ Hin,
                        float* __restrict__ Hout) {
    int row = blockIdx.x;
    int t = threadIdx.x;  // 128
    int cnt = nnz[row];
    const int* cp = colsI + (size_t)row * MAXNBR;
    float4 acc = make_float4(0.f, 0.f, 0.f, 0.f);
    for (int j = 0; j < cnt; ++j) {
        int c = cp[j];
        float wgt = dis[c];
        float4 v = *(const float4*)(Hin + (size_t)c * HH + t * 4);
        acc.x += wgt * v.x; acc.y += wgt * v.y; acc.z += wgt * v.z; acc.w += wgt * v.w;
    }
    float di = dis[row];
    acc.x *= di; acc.y *= di; acc.z *= di; acc.w *= di;
    *(float4*)(Hout + (size_t)row * HH + t * 4) = acc;
}

__global__ void spmm64(const int* __restrict__ nnz, const int* __restrict__ colsI,
                       const float* __restrict__ dis, const float* __restrict__ Hin,
                       float* __restrict__ Hout) {
    int row = blockIdx.x;
    int t = threadIdx.x;  // 64
    int cnt = nnz[row];
    const int* cp = colsI + (size_t)row * MAXNBR;
    float acc = 0.f;
    for (int j = 0; j < cnt; ++j) {
        int c = cp[j];
        acc += dis[c] * Hin[(size_t)c * CC + t];
    }
    Hout[(size_t)row * CC + t] = dis[row] * acc;
}

// ---------------- PairNorm ----------------

__global__ void colsum_kernel(const float* __restrict__ X, float* __restrict__ colsum) {
    int t = threadIdx.x;  // 256
    float s0 = 0.f, s1 = 0.f;
    for (int r = blockIdx.x; r < NN; r += gridDim.x) {
        const float* row = X + (size_t)r * HH;
        s0 += row[t];
        s1 += row[t + 256];
    }
    atomicAdd(&colsum[t], s0);
    atomicAdd(&colsum[t + 256], s1);
}

__global__ void sumsq_kernel(const float* __restrict__ X, const float* __restrict__ colsum,
                             float* __restrict__ stats) {
    const float4* X4 = (const float4*)X;
    const float4* M4 = (const float4*)colsum;
    const float inv = 1.0f / (float)NN;
    float local = 0.f;
    int total = NN * HH / 4;
    for (int i = blockIdx.x * blockDim.x + threadIdx.x; i < total; i += gridDim.x * blockDim.x) {
        float4 v = X4[i];
        float4 m = M4[i & 127];
        float dx = v.x - m.x * inv; local += dx * dx;
        float dy = v.y - m.y * inv; local += dy * dy;
        float dz = v.z - m.z * inv; local += dz * dz;
        float dw = v.w - m.w * inv; local += dw * dw;
    }
#pragma unroll
    for (int o = 32; o > 0; o >>= 1) local += __shfl_down(local, o);
    __shared__ float red[4];
    int wid = threadIdx.x >> 6, lane = threadIdx.x & 63;
    if (lane == 0) red[wid] = local;
    __syncthreads();
    if (threadIdx.x == 0) atomicAdd(stats, red[0] + red[1] + red[2] + red[3]);
}

__global__ void pn_apply(const float* __restrict__ X, const float* __restrict__ colsum,
                         const float* __restrict__ stats, float* __restrict__ Y) {
    int i = blockIdx.x * blockDim.x + threadIdx.x;   // 1048576 float4s exactly
    const float inv = 1.0f / (float)NN;
    float s = 1.0f / sqrtf(1e-6f + stats[0] * inv);
    float4 v = ((const float4*)X)[i];
    float4 m = ((const float4*)colsum)[i & 127];
    v.x = fmaxf((v.x - m.x * inv) * s, 0.f);
    v.y = fmaxf((v.y - m.y * inv) * s, 0.f);
    v.z = fmaxf((v.z - m.z * inv) * s, 0.f);
    v.w = fmaxf((v.w - m.w * inv) * s, 0.f);
    ((float4*)Y)[i] = v;
}

// ---------------- launch ----------------

extern "C" void kernel_launch(void* const* d_in, const int* in_sizes, int n_in,
                              void* d_out, int out_size, void* d_ws, size_t ws_size,
                              hipStream_t stream) {
    const float* x   = (const float*)d_in[0];
    const float* adj = (const float*)d_in[1];
    const float* W0  = (const float*)d_in[2];
    const float* W1  = (const float*)d_in[3];
    const float* W2  = (const float*)d_in[4];
    const float* S0  = (const float*)d_in[5];
    const float* S1  = (const float*)d_in[6];
    const float* S2  = (const float*)d_in[7];
    float* out = (float*)d_out;

    char* w = (char*)d_ws;
    size_t off = 0;
    auto alloc = [&](size_t b) { size_t r = off; off = (off + b + 255) & ~(size_t)255; return r; };
    unsigned* hist1 = (unsigned*)(w + alloc(65536 * 4));
    unsigned* hist2 = (unsigned*)(w + alloc(65536 * 4));
    unsigned* sel   = (unsigned*)(w + alloc(256));
    float* colsum   = (float*)(w + alloc(HH * 4));
    float* stats    = (float*)(w + alloc(256));
    size_t zero_end = off;
    int* nnz   = (int*)(w + alloc(NN * 4));
    int* colsI = (int*)(w + alloc((size_t)NN * MAXNBR * 4));
    float* dis = (float*)(w + alloc(NN * 4));
    float* Wm0 = (float*)(w + alloc((size_t)HH * FF * 4));
    float* Wm1 = (float*)(w + alloc((size_t)HH * HH * 4));
    float* Wm2 = (float*)(w + alloc((size_t)CC * HH * 4));
    float* hA  = (float*)(w + alloc((size_t)NN * HH * 4));
    float* hB  = (float*)(w + alloc((size_t)NN * HH * 4));
    float* h3  = (float*)(w + alloc((size_t)NN * CC * 4));
    (void)ws_size; (void)in_sizes; (void)n_in; (void)out_size;

    hipMemsetAsync(d_ws, 0, zero_end, stream);

    // threshold (exact radix select)
    hist_kernel<<<NS_TOTAL / 256, 256, 0, stream>>>(S0, S1, S2, hist1, nullptr, 0);
    select_kernel<<<1, 256, 0, stream>>>(hist1, sel, KSEL, 0);
    hist_kernel<<<NS_TOTAL / 256, 256, 0, stream>>>(S0, S1, S2, hist2, sel, 1);
    select_kernel<<<1, 256, 0, stream>>>(hist2, sel, 0u, 1);

    // masked weights
    mask_kernel<<<NS_TOTAL / 256, 256, 0, stream>>>(W0, W1, W2, S0, S1, S2, Wm0, Wm1, Wm2, sel);

    // adjacency -> CSR + deg^-1/2  (single 256MB pass)
    deg_kernel<<<NN, 256, 0, stream>>>(adj, nnz, colsI, dis);

    // h0 = x @ Wm0^T ; h1 = h0 @ Wm1^T
    gemm_nt64<<<dim3(NN / 64, HH / 64), 256, 0, stream>>>(x, Wm0, hA, NN, HH, FF);
    gemm_nt64<<<dim3(NN / 64, HH / 64), 256, 0, stream>>>(hA, Wm1, hB, NN, HH, HH);

    // aggregation
    spmm512<<<NN, 128, 0, stream>>>(nnz, colsI, dis, hB, hA);

    // pairnorm + relu
    colsum_kernel<<<256, 256, 0, stream>>>(hA, colsum);
    sumsq_kernel<<<1024, 256, 0, stream>>>(hA, colsum, stats);
    pn_apply<<<(NN * HH / 4) / 256, 256, 0, stream>>>(hA, colsum, stats, hB);

    // h3 = hB @ Wm2^T ; out = adj_n @ h3
    gemm_nt64<<<dim3(NN / 64, CC / 64), 256, 0, stream>>>(hB, Wm2, h3, NN, CC, HH);
    spmm64<<<NN, 64, 0, stream>>>(nnz, colsI, dis, h3, out);
}

// Round 2
// 359.087 us; speedup vs baseline: 1.5501x; 1.5501x over previous
//
#include <hip/hip_runtime.h>
#include <hip/hip_bf16.h>

#define NN 8192
#define FF 512
#define HH 512
#define CC 64
#define NS_TOTAL 557056      // 512*512 + 512*512 + 64*512
#define KSEL 278529u         // 1 + round(0.5 * (557056-1))
#define MAXNBR 96

// ---------------- threshold: exact 4x8-bit radix select over |S| bit patterns ----------------
// sel[2] = final threshold float bits; sel[4] = prefix; sel[5] = remaining rank

__global__ __launch_bounds__(256) void hist8_kernel(const float* __restrict__ S0,
                                                    const float* __restrict__ S1,
                                                    const float* __restrict__ S2,
                                                    unsigned* __restrict__ hist,
                                                    const unsigned* __restrict__ sel, int pass) {
    __shared__ unsigned lh[256];
    lh[threadIdx.x] = 0;
    __syncthreads();
    unsigned prefix = 0, pmask = 0;
    int shift = 24 - 8 * pass;
    if (pass > 0) {
        prefix = sel[4];
        pmask = 0xFFFFFFFFu << (shift + 8);
    }
    int stride = gridDim.x * blockDim.x;
    for (int idx = blockIdx.x * blockDim.x + threadIdx.x; idx < NS_TOTAL; idx += stride) {
        float v = (idx < 262144) ? S0[idx] : (idx < 524288) ? S1[idx - 262144] : S2[idx - 524288];
        unsigned key = __float_as_uint(fabsf(v));
        if ((key & pmask) == prefix)
            atomicAdd(&lh[(key >> shift) & 0xffu], 1u);
    }
    __syncthreads();
    unsigned c = lh[threadIdx.x];
    if (c) atomicAdd(&hist[threadIdx.x], c);
}

__global__ void select8_kernel(const unsigned* __restrict__ hist, unsigned* __restrict__ sel,
                               int pass) {
    if (threadIdx.x != 0) return;
    unsigned k = (pass == 0) ? KSEL : sel[5];
    unsigned prefix = (pass == 0) ? 0u : sel[4];
    unsigned cum = 0; int b = 0;
    while (b < 255 && cum + hist[b] < k) { cum += hist[b]; b++; }
    int shift = 24 - 8 * pass;
    sel[4] = prefix | ((unsigned)b << shift);
    sel[5] = k - cum;
    if (pass == 3) sel[2] = prefix | (unsigned)b;
}

// ---------------- masked weights ----------------

__global__ void mask_kernel(const float* __restrict__ W0, const float* __restrict__ W1,
                            const float* __restrict__ W2, const float* __restrict__ S0,
                            const float* __restrict__ S1, const float* __restrict__ S2,
                            float* __restrict__ Wm0, float* __restrict__ Wm1,
                            float* __restrict__ Wm2, const unsigned* __restrict__ sel) {
    int idx = blockIdx.x * blockDim.x + threadIdx.x;
    if (idx >= NS_TOTAL) return;
    float thr = __uint_as_float(sel[2]);
    if (idx < 262144) {
        Wm0[idx] = W0[idx] * ((fabsf(S0[idx]) > thr) ? 1.f : 0.f);
    } else if (idx < 524288) {
        int i = idx - 262144;
        Wm1[i] = W1[i] * ((fabsf(S1[i]) > thr) ? 1.f : 0.f);
    } else {
        int i = idx - 524288;
        Wm2[i] = W2[i] * ((fabsf(S2[i]) > thr) ? 1.f : 0.f);
    }
}

// ---------------- adjacency: degree + neighbor extraction (one pass over 256MB) ----------------

__global__ __launch_bounds__(256) void deg_kernel(const float* __restrict__ adj,
                                                  int* __restrict__ nnz, int* __restrict__ colsI,
                                                  float* __restrict__ dis) {
    int row = blockIdx.x;
    __shared__ int cnt;
    if (threadIdx.x == 0) cnt = 0;
    __syncthreads();
    const float4* arow = (const float4*)(adj + (size_t)row * NN);
    int* cp = colsI + (size_t)row * MAXNBR;
    for (int c4 = threadIdx.x; c4 < NN / 4; c4 += 256) {
        float4 v = arow[c4];
        int base = c4 * 4;
        float vv[4] = {v.x, v.y, v.z, v.w};
#pragma unroll
        for (int kq = 0; kq < 4; ++kq) {
            int col = base + kq;
            if (vv[kq] != 0.f || col == row) {
                int s = atomicAdd(&cnt, 1);
                if (s < MAXNBR) cp[s] = col;
            }
        }
    }
    __syncthreads();
    if (threadIdx.x == 0) {
        int c = cnt;
        nnz[row] = (c < MAXNBR) ? c : MAXNBR;
        dis[row] = rsqrtf((float)c);   // deg >= 1 always (self loop)
    }
}

// ---------------- f32 GEMM: C[M,Nn] = A[M,K] * B[Nn,K]^T ----------------

__global__ __launch_bounds__(256) void gemm_nt64(const float* __restrict__ A,
                                                 const float* __restrict__ B,
                                                 float* __restrict__ C,
                                                 int M, int Nn, int K) {
    __shared__ float As[16][68];
    __shared__ float Bs[16][68];
    const int bm = blockIdx.x * 64;
    const int bn = blockIdx.y * 64;
    const int tid = threadIdx.x;
    const int tn = tid & 15;    // col group (coalesced C writes)
    const int tm = tid >> 4;    // row group
    float acc[4][4] = {{0.f}};
    for (int k0 = 0; k0 < K; k0 += 16) {
        int li = tid * 4;
        int r = li >> 4;     // 0..63
        int c = li & 15;     // 0,4,8,12
        float4 av = *(const float4*)(A + (size_t)(bm + r) * K + (k0 + c));
        float4 bv = *(const float4*)(B + (size_t)(bn + r) * K + (k0 + c));
        As[c + 0][r] = av.x; As[c + 1][r] = av.y; As[c + 2][r] = av.z; As[c + 3][r] = av.w;
        Bs[c + 0][r] = bv.x; Bs[c + 1][r] = bv.y; Bs[c + 2][r] = bv.z; Bs[c + 3][r] = bv.w;
        __syncthreads();
#pragma unroll
        for (int kk = 0; kk < 16; ++kk) {
            float4 a = *(const float4*)&As[kk][tm * 4];
            float4 b = *(const float4*)&Bs[kk][tn * 4];
            acc[0][0] += a.x * b.x; acc[0][1] += a.x * b.y; acc[0][2] += a.x * b.z; acc[0][3] += a.x * b.w;
            acc[1][0] += a.y * b.x; acc[1][1] += a.y * b.y; acc[1][2] += a.y * b.z; acc[1][3] += a.y * b.w;
            acc[2][0] += a.z * b.x; acc[2][1] += a.z * b.y; acc[2][2] += a.z * b.z; acc[2][3] += a.z * b.w;
            acc[3][0] += a.w * b.x; acc[3][1] += a.w * b.y; acc[3][2] += a.w * b.z; acc[3][3] += a.w * b.w;
        }
        __syncthreads();
    }
#pragma unroll
    for (int i = 0; i < 4; ++i) {
        float4 o = make_float4(acc[i][0], acc[i][1], acc[i][2], acc[i][3]);
        *(float4*)(C + (size_t)(bm + tm * 4 + i) * Nn + bn + tn * 4) = o;
    }
}

// ---------------- SpMM: Hout[row,:] = dis[row] * sum_nbr dis[c] * Hin[c,:] ----------------

__global__ void spmm512(const int* __restrict__ nnz, const int* __restrict__ colsI,
                        const float* __restrict__ dis, const float* __restrict__ Hin,
                        float* __restrict__ Hout) {
    int row = blockIdx.x;
    int t = threadIdx.x;  // 128
    int cnt = nnz[row];
    const int* cp = colsI + (size_t)row * MAXNBR;
    float4 acc = make_float4(0.f, 0.f, 0.f, 0.f);
    for (int j = 0; j < cnt; ++j) {
        int c = cp[j];
        float wgt = dis[c];
        float4 v = *(const float4*)(Hin + (size_t)c * HH + t * 4);
        acc.x += wgt * v.x; acc.y += wgt * v.y; acc.z += wgt * v.z; acc.w += wgt * v.w;
    }
    float di = dis[row];
    acc.x *= di; acc.y *= di; acc.z *= di; acc.w *= di;
    *(float4*)(Hout + (size_t)row * HH + t * 4) = acc;
}

__global__ void spmm64(const int* __restrict__ nnz, const int* __restrict__ colsI,
                       const float* __restrict__ dis, const float* __restrict__ Hin,
                       float* __restrict__ Hout) {
    int row = blockIdx.x;
    int t = threadIdx.x;  // 64
    int cnt = nnz[row];
    const int* cp = colsI + (size_t)row * MAXNBR;
    float acc = 0.f;
    for (int j = 0; j < cnt; ++j) {
        int c = cp[j];
        acc += dis[c] * Hin[(size_t)c * CC + t];
    }
    Hout[(size_t)row * CC + t] = dis[row] * acc;
}

// ---------------- PairNorm ----------------

__global__ void colsum_kernel(const float* __restrict__ X, float* __restrict__ colsum) {
    int t = threadIdx.x;  // 256
    float s0 = 0.f, s1 = 0.f;
    for (int r = blockIdx.x; r < NN; r += gridDim.x) {
        const float* row = X + (size_t)r * HH;
        s0 += row[t];
        s1 += row[t + 256];
    }
    atomicAdd(&colsum[t], s0);
    atomicAdd(&colsum[t + 256], s1);
}

__global__ void sumsq_kernel(const float* __restrict__ X, const float* __restrict__ colsum,
                             float* __restrict__ stats) {
    const float4* X4 = (const float4*)X;
    const float4* M4 = (const float4*)colsum;
    const float inv = 1.0f / (float)NN;
    float local = 0.f;
    int total = NN * HH / 4;
    for (int i = blockIdx.x * blockDim.x + threadIdx.x; i < total; i += gridDim.x * blockDim.x) {
        float4 v = X4[i];
        float4 m = M4[i & 127];
        float dx = v.x - m.x * inv; local += dx * dx;
        float dy = v.y - m.y * inv; local += dy * dy;
        float dz = v.z - m.z * inv; local += dz * dz;
        float dw = v.w - m.w * inv; local += dw * dw;
    }
#pragma unroll
    for (int o = 32; o > 0; o >>= 1) local += __shfl_down(local, o);
    __shared__ float red[4];
    int wid = threadIdx.x >> 6, lane = threadIdx.x & 63;
    if (lane == 0) red[wid] = local;
    __syncthreads();
    if (threadIdx.x == 0) atomicAdd(stats, red[0] + red[1] + red[2] + red[3]);
}

__global__ void pn_apply(const float* __restrict__ X, const float* __restrict__ colsum,
                         const float* __restrict__ stats, float* __restrict__ Y) {
    int i = blockIdx.x * blockDim.x + threadIdx.x;   // 1048576 float4s exactly
    const float inv = 1.0f / (float)NN;
    float s = 1.0f / sqrtf(1e-6f + stats[0] * inv);
    float4 v = ((const float4*)X)[i];
    float4 m = ((const float4*)colsum)[i & 127];
    v.x = fmaxf((v.x - m.x * inv) * s, 0.f);
    v.y = fmaxf((v.y - m.y * inv) * s, 0.f);
    v.z = fmaxf((v.z - m.z * inv) * s, 0.f);
    v.w = fmaxf((v.w - m.w * inv) * s, 0.f);
    ((float4*)Y)[i] = v;
}

// ---------------- launch ----------------

extern "C" void kernel_launch(void* const* d_in, const int* in_sizes, int n_in,
                              void* d_out, int out_size, void* d_ws, size_t ws_size,
                              hipStream_t stream) {
    const float* x   = (const float*)d_in[0];
    const float* adj = (const float*)d_in[1];
    const float* W0  = (const float*)d_in[2];
    const float* W1  = (const float*)d_in[3];
    const float* W2  = (const float*)d_in[4];
    const float* S0  = (const float*)d_in[5];
    const float* S1  = (const float*)d_in[6];
    const float* S2  = (const float*)d_in[7];
    float* out = (float*)d_out;

    char* w = (char*)d_ws;
    size_t off = 0;
    auto alloc = [&](size_t b) { size_t r = off; off = (off + b + 255) & ~(size_t)255; return r; };
    unsigned* hists = (unsigned*)(w + alloc(4 * 256 * 4));   // hists[pass][256]
    unsigned* sel   = (unsigned*)(w + alloc(256));
    float* colsum   = (float*)(w + alloc(HH * 4));
    float* stats    = (float*)(w + alloc(256));
    size_t zero_end = off;
    int* nnz   = (int*)(w + alloc(NN * 4));
    int* colsI = (int*)(w + alloc((size_t)NN * MAXNBR * 4));
    float* dis = (float*)(w + alloc(NN * 4));
    float* Wm0 = (float*)(w + alloc((size_t)HH * FF * 4));
    float* Wm1 = (float*)(w + alloc((size_t)HH * HH * 4));
    float* Wm2 = (float*)(w + alloc((size_t)CC * HH * 4));
    float* hA  = (float*)(w + alloc((size_t)NN * HH * 4));
    float* hB  = (float*)(w + alloc((size_t)NN * HH * 4));
    float* h3  = (float*)(w + alloc((size_t)NN * CC * 4));
    (void)ws_size; (void)in_sizes; (void)n_in; (void)out_size;

    hipMemsetAsync(d_ws, 0, zero_end, stream);

    // threshold: exact radix select, 4 x 8-bit passes with LDS-private histograms
    for (int p = 0; p < 4; ++p) {
        hist8_kernel<<<256, 256, 0, stream>>>(S0, S1, S2, hists + p * 256, sel, p);
        select8_kernel<<<1, 64, 0, stream>>>(hists + p * 256, sel, p);
    }

    // masked weights
    mask_kernel<<<NS_TOTAL / 256, 256, 0, stream>>>(W0, W1, W2, S0, S1, S2, Wm0, Wm1, Wm2, sel);

    // adjacency -> CSR + deg^-1/2  (single 256MB pass)
    deg_kernel<<<NN, 256, 0, stream>>>(adj, nnz, colsI, dis);

    // h0 = x @ Wm0^T ; h1 = h0 @ Wm1^T
    gemm_nt64<<<dim3(NN / 64, HH / 64), 256, 0, stream>>>(x, Wm0, hA, NN, HH, FF);
    gemm_nt64<<<dim3(NN / 64, HH / 64), 256, 0, stream>>>(hA, Wm1, hB, NN, HH, HH);

    // aggregation
    spmm512<<<NN, 128, 0, stream>>>(nnz, colsI, dis, hB, hA);

    // pairnorm + relu
    colsum_kernel<<<256, 256, 0, stream>>>(hA, colsum);
    sumsq_kernel<<<1024, 256, 0, stream>>>(hA, colsum, stats);
    pn_apply<<<(NN * HH / 4) / 256, 256, 0, stream>>>(hA, colsum, stats, hB);

    // h3 = hB @ Wm2^T ; out = adj_n @ h3
    gemm_nt64<<<dim3(NN / 64, CC / 64), 256, 0, stream>>>(hB, Wm2, h3, NN, CC, HH);
    spmm64<<<NN, 64, 0, stream>>>(nnz, colsI, dis, h3, out);
}